// Round 1
// baseline (75.688 us; speedup 1.0000x reference)
//
#include <hip/hip_runtime.h>
#include <math.h>

#define N_DENSE 13
#define N_SPARSE 26
#define SPARSE_DIM 100
#define N_FIELD 39            // 13 + 26
#define KDIM 16
#define ROW_F (N_FIELD * KDIM)   // 624 floats per feature row of v
#define ROW_Q (ROW_F / 4)        // 156 float4 per feature row
#define ROWS_PER_BLOCK 16
#define THREADS 256

__global__ __launch_bounds__(THREADS) void ffm_kernel(
    const float* __restrict__ x,     // [B, 39]
    const float* __restrict__ w,     // [2613]
    const float* __restrict__ bias,  // [1]
    const float* __restrict__ v,     // [2613, 39, 16]
    float* __restrict__ out,         // [B]
    int B)
{
    // Stage the 13 dense-feature v rows (first 13*624 floats of v) in LDS:
    // every row of the batch uses them. 32448 B.
    __shared__ float ldsDense[N_DENSE * ROW_F];
    const float4* v4 = reinterpret_cast<const float4*>(v);
    float4* lds4 = reinterpret_cast<float4*>(ldsDense);
    for (int i = threadIdx.x; i < N_DENSE * ROW_Q; i += THREADS)
        lds4[i] = v4[i];
    __syncthreads();

    const int g = threadIdx.x >> 4;   // group (row) within block, 0..15
    const int l = threadIdx.x & 15;   // lane within group
    const int row = blockIdx.x * ROWS_PER_BLOCK + g;
    if (row >= B) return;

    const float* xr = x + row * (N_DENSE + N_SPARSE);

    // Per-lane accumulators: quads p = l + 16*i of the 156-float4 row image.
    // Each quad is a single field f = p>>2, k-range q = p&3 = l&3.
    float4 acc[10];
#pragma unroll
    for (int i = 0; i < 10; ++i) acc[i] = make_float4(0.f, 0.f, 0.f, 0.f);

    // ---- dense features (from LDS) ----
#pragma unroll
    for (int j = 0; j < N_DENSE; ++j) {
        float xv = xr[j];
        const float4* b = lds4 + j * ROW_Q;
#pragma unroll
        for (int i = 0; i < 10; ++i) {
            if (i < 9 || l < 12) {          // p = l+16i < 156
                float4 t = b[l + 16 * i];
                acc[i].x += xv * t.x;
                acc[i].y += xv * t.y;
                acc[i].z += xv * t.z;
                acc[i].w += xv * t.w;
            }
        }
    }

    // ---- sparse features (gathered, one-hot value = 1.0) ----
    int nidx[N_SPARSE];
#pragma unroll
    for (int s = 0; s < N_SPARSE; ++s)
        nidx[s] = N_DENSE + s * SPARSE_DIM + (int)xr[N_DENSE + s];

    for (int s = 0; s < N_SPARSE; ++s) {
        const float4* b = v4 + (size_t)nidx[s] * ROW_Q;
#pragma unroll
        for (int i = 0; i < 10; ++i) {
            if (i < 9 || l < 12) {
                float4 t = b[l + 16 * i];
                acc[i].x += t.x;
                acc[i].y += t.y;
                acc[i].z += t.z;
                acc[i].w += t.w;
            }
        }
    }

    // ---- reductions ----
    // per-lane: partial s over this lane's fields, and exact sum of squares
    float4 s4 = make_float4(0.f, 0.f, 0.f, 0.f);
    float4 q4 = make_float4(0.f, 0.f, 0.f, 0.f);
#pragma unroll
    for (int i = 0; i < 10; ++i) {
        s4.x += acc[i].x; s4.y += acc[i].y; s4.z += acc[i].z; s4.w += acc[i].w;
        q4.x += acc[i].x * acc[i].x;
        q4.y += acc[i].y * acc[i].y;
        q4.z += acc[i].z * acc[i].z;
        q4.w += acc[i].w * acc[i].w;
    }
    // reduce across the 4 lanes sharing the same k-quad (l, l+4, l+8, l+12)
#pragma unroll
    for (int m = 4; m <= 8; m <<= 1) {
        s4.x += __shfl_xor(s4.x, m); s4.y += __shfl_xor(s4.y, m);
        s4.z += __shfl_xor(s4.z, m); s4.w += __shfl_xor(s4.w, m);
        q4.x += __shfl_xor(q4.x, m); q4.y += __shfl_xor(q4.y, m);
        q4.z += __shfl_xor(q4.z, m); q4.w += __shfl_xor(q4.w, m);
    }
    // c(q) = sum over this quad's 4 k of (s_k^2 - sq_k)
    float c = (s4.x * s4.x - q4.x) + (s4.y * s4.y - q4.y) +
              (s4.z * s4.z - q4.z) + (s4.w * s4.w - q4.w);
    // sum the 4 quad classes (lanes differing in bits 0..1)
    c += __shfl_xor(c, 1);
    c += __shfl_xor(c, 2);

    // ---- linear part (redundant on all 16 lanes; lane 0 stores) ----
    float lin = bias[0];
#pragma unroll
    for (int j = 0; j < N_DENSE; ++j) lin += xr[j] * w[j];
#pragma unroll
    for (int s = 0; s < N_SPARSE; ++s) lin += w[nidx[s]];

    float logit = lin + 0.5f * c;
    if (l == 0) out[row] = 1.f / (1.f + expf(-logit));
}

extern "C" void kernel_launch(void* const* d_in, const int* in_sizes, int n_in,
                              void* d_out, int out_size, void* d_ws, size_t ws_size,
                              hipStream_t stream) {
    const float* x    = (const float*)d_in[0];
    const float* w    = (const float*)d_in[1];
    const float* bias = (const float*)d_in[2];
    const float* v    = (const float*)d_in[3];
    float* out = (float*)d_out;

    int B = in_sizes[0] / (N_DENSE + N_SPARSE);
    int grid = (B + ROWS_PER_BLOCK - 1) / ROWS_PER_BLOCK;
    ffm_kernel<<<grid, THREADS, 0, stream>>>(x, w, bias, v, out, B);
}